// Round 7
// baseline (854.457 us; speedup 1.0000x reference)
//
#include <hip/hip_runtime.h>
#include <hip/hip_bf16.h>

#define N_NODES 38332
#define POI_LEN 38333
#define CAT_LEN 400
#define POI_DIM 300
#define CAT_DIM 100
#define N_EDGES (N_NODES * 32)
#define NEG_SLOPE 0.01f
#define N_CHUNKS ((N_NODES + 255) / 256)  // 150
#define PROJ_CHUNK 20
#define PROJ_ROWS 32
#define B1 ((N_NODES + 127) / 128)        // 300 coarse dst-buckets
#define SPLIT_CHUNK 4096
#define NSPLIT ((N_EDGES + SPLIT_CHUNK - 1) / SPLIT_CHUNK)  // 300
#define PLACE_CAP 8192

// ---------------- CSR build ----------------

__global__ void k_zero(int* __restrict__ cnt, float* __restrict__ h128) {
  int i = blockIdx.x * 256 + threadIdx.x;
  if (i < N_NODES) cnt[i] = 0;
  if (i < 128) h128[i] = 0.f;
}

__global__ void k_count(const int* __restrict__ dst, int* __restrict__ cnt) {
  int e = blockIdx.x * 256 + threadIdx.x;
  if (e < N_EDGES) atomicAdd(&cnt[dst[e]], 1);
}

__global__ __launch_bounds__(256) void k_scan1(const int* __restrict__ cnt,
                                               int* __restrict__ partial,
                                               float* __restrict__ dinv) {
  __shared__ int sb[256];
  int tid = threadIdx.x;
  int i = blockIdx.x * 256 + tid;
  int v = (i < N_NODES) ? cnt[i] : 0;
  if (i < N_NODES) dinv[i] = 1.0f / sqrtf((float)(v + 1));  // deg incl self loop
  sb[tid] = v;
  __syncthreads();
  for (int off = 128; off; off >>= 1) {
    if (tid < off) sb[tid] += sb[tid + off];
    __syncthreads();
  }
  if (tid == 0) partial[blockIdx.x] = sb[0];
}

__global__ __launch_bounds__(256) void k_scan2(int* __restrict__ partial) {
  __shared__ int sb[256];
  int tid = threadIdx.x;
  int v = (tid < N_CHUNKS) ? partial[tid] : 0;
  sb[tid] = v;
  __syncthreads();
  for (int off = 1; off < 256; off <<= 1) {
    int t = (tid >= off) ? sb[tid - off] : 0;
    __syncthreads();
    sb[tid] += t;
    __syncthreads();
  }
  if (tid < N_CHUNKS) partial[tid] = sb[tid] - v;  // exclusive
}

__global__ __launch_bounds__(256) void k_scan3(const int* __restrict__ cnt,
                                               const int* __restrict__ partial,
                                               int* __restrict__ row_start) {
  __shared__ int sb[256];
  int tid = threadIdx.x;
  int i = blockIdx.x * 256 + tid;
  int v = (i < N_NODES) ? cnt[i] : 0;
  sb[tid] = v;
  __syncthreads();
  for (int off = 1; off < 256; off <<= 1) {
    int t = (tid >= off) ? sb[tid - off] : 0;
    __syncthreads();
    sb[tid] += t;
    __syncthreads();
  }
  if (i < N_NODES) row_start[i] = partial[blockIdx.x] + sb[tid] - v;
  if (i == N_NODES - 1) row_start[N_NODES] = partial[blockIdx.x] + sb[tid];
}

__global__ void k_binit(const int* __restrict__ row_start, int* __restrict__ bcur) {
  int b = blockIdx.x * 256 + threadIdx.x;
  if (b < B1) bcur[b] = row_start[b * 128];
}

// Level-1: bucket (src,dst) pairs by dst>>7 into per-bucket contiguous staging
// ranges (writes from one CU land in short contiguous runs).
__global__ __launch_bounds__(256) void k_split(const int* __restrict__ src,
                                               const int* __restrict__ dst,
                                               int* __restrict__ bcur,
                                               int2* __restrict__ staging) {
  __shared__ int hist[B1];
  __shared__ int lbase[B1];
  __shared__ int lcur[B1];
  int tid = threadIdx.x;
  int base = blockIdx.x * SPLIT_CHUNK;
  int n = N_EDGES - base;
  if (n > SPLIT_CHUNK) n = SPLIT_CHUNK;
  for (int b = tid; b < B1; b += 256) {
    hist[b] = 0;
    lcur[b] = 0;
  }
  __syncthreads();
  for (int i = tid; i < n; i += 256) atomicAdd(&hist[dst[base + i] >> 7], 1);
  __syncthreads();
  for (int b = tid; b < B1; b += 256) {
    int c = hist[b];
    lbase[b] = c ? atomicAdd(&bcur[b], c) : 0;
  }
  __syncthreads();
  for (int i = tid; i < n; i += 256) {
    int d = dst[base + i];
    int s = src[base + i];
    int b = d >> 7;
    int off = atomicAdd(&lcur[b], 1);
    staging[lbase[b] + off] = make_int2(s, d);
  }
}

// Level-2: one block per bucket; exact per-dst placement in LDS, coalesced copy out.
__global__ __launch_bounds__(256) void k_place(const int2* __restrict__ staging,
                                               const int* __restrict__ row_start,
                                               int* __restrict__ csr_src) {
  __shared__ int cur[128];
  __shared__ int buf[PLACE_CAP];
  int b = blockIdx.x;
  int d0 = b * 128;
  int d1 = d0 + 128;
  if (d1 > N_NODES) d1 = N_NODES;
  int tid = threadIdx.x;
  int e0 = row_start[d0];
  int e1 = row_start[d1];
  int cnt = e1 - e0;
  if (tid < d1 - d0) cur[tid] = row_start[d0 + tid] - e0;
  __syncthreads();
  for (int i = tid; i < cnt; i += 256) {
    int2 p = staging[e0 + i];
    int pos = atomicAdd(&cur[p.y - d0], 1);
    if (pos < PLACE_CAP) buf[pos] = p.x;
    else csr_src[e0 + pos] = p.x;  // overflow fallback (statistically never)
  }
  __syncthreads();
  for (int i = tid; i < cnt && i < PLACE_CAP; i += 256) csr_src[e0 + i] = buf[i];
}

// ---------------- projection GEMM: C[M][64] = A[M][K] @ W[K][64] ----------
// 32 rows/block, 8 rows/wave: per k4 = 4 W loads + 8 ds_read_b128 + 32 FMA
// (73% FMA density); 1198 blocks for POI keeps ~19 waves/CU resident.

__global__ __launch_bounds__(256) void k_proj(const float* __restrict__ A,
                                              const float* __restrict__ W,
                                              float* __restrict__ C, int M, int K) {
  __shared__ float sA[PROJ_ROWS][24];
  int tid = threadIdx.x;
  int lane = tid & 63;
  int wv = tid >> 6;
  int row0 = blockIdx.x * PROJ_ROWS;
  float acc[8] = {0.f, 0.f, 0.f, 0.f, 0.f, 0.f, 0.f, 0.f};

  for (int c = 0; c < K; c += PROJ_CHUNK) {
    __syncthreads();
    for (int idx = tid; idx < PROJ_ROWS * PROJ_CHUNK; idx += 256) {
      int r = idx / PROJ_CHUNK;
      int k = idx % PROJ_CHUNK;
      int row = row0 + r;
      sA[r][k] = (row < M) ? A[(size_t)row * K + c + k] : 0.f;
    }
    __syncthreads();
#pragma unroll
    for (int k4 = 0; k4 < PROJ_CHUNK / 4; k4++) {
      int k = c + k4 * 4;
      float w0 = W[(k + 0) * 64 + lane];
      float w1 = W[(k + 1) * 64 + lane];
      float w2 = W[(k + 2) * 64 + lane];
      float w3 = W[(k + 3) * 64 + lane];
#pragma unroll
      for (int r = 0; r < 8; r++) {
        const float4 f4 = *(const float4*)&sA[wv * 8 + r][k4 * 4];
        acc[r] += f4.x * w0 + f4.y * w1 + f4.z * w2 + f4.w * w3;
      }
    }
  }
#pragma unroll
  for (int r = 0; r < 8; r++) {
    int row = row0 + wv * 8 + r;
    if (row < M) C[(size_t)row * 64 + lane] = acc[r];
  }
}

// ---------------- gather + combine -> flat hs ----------------

__global__ __launch_bounds__(256) void k_gather(
    const float* __restrict__ x, const float* __restrict__ proj_poi,
    const float* __restrict__ proj_cat, const float* __restrict__ W_in,
    const float* __restrict__ dinv, float* __restrict__ hs) {
  int lane = threadIdx.x & 63;
  int w = threadIdx.x >> 6;
  int node = blockIdx.x * 4 + w;
  int pid = (int)x[node * 5 + 0];
  int cid = (int)x[node * 5 + 1];
  float x2 = x[node * 5 + 2];
  float x3 = x[node * 5 + 3];
  float x4 = x[node * 5 + 4];
  float v = proj_poi[(size_t)pid * 64 + lane] + proj_cat[(size_t)cid * 64 + lane] +
            x2 * W_in[400 * 64 + lane] + x3 * W_in[401 * 64 + lane] +
            x4 * W_in[402 * 64 + lane];
  hs[(size_t)node * 64 + lane] = v * dinv[node];
}

// ---------------- middle transform: hs = (feat @ W) * dinv ----------------

__global__ __launch_bounds__(256) void k_xform(const float* __restrict__ feat,
                                               const float* __restrict__ W,
                                               const float* __restrict__ dinv,
                                               float* __restrict__ hs) {
  __shared__ float sW[64 * 64];
  int tid = threadIdx.x;
  int lane = tid & 63;
  int w = tid >> 6;
  for (int k = tid; k < 64 * 64; k += 256) sW[k] = W[k];
  __syncthreads();
  int node = blockIdx.x * 4 + w;
  float f = feat[(size_t)node * 64 + lane];
  float acc = 0.f;
#pragma unroll
  for (int k = 0; k < 64; k++) {
    float fk = __shfl(f, k, 64);
    acc += fk * sW[k * 64 + lane];
  }
  hs[(size_t)node * 64 + lane] = acc * dinv[node];
}

// ---------------- aggregation, float4-lane / deep MLP ----------------
// wave = 1 dst node. lane = eslot(4) x ch16(16); each lane loads float4.
// Main loop: 8 gathers per iter = 32 edges = 32 cache lines in flight/wave;
// cascade 8->4->1 so low-degree nodes don't serialize.

template <int MODE>
__global__ __launch_bounds__(256) void k_agg(const float* __restrict__ hs,
                                             const int* __restrict__ row_start,
                                             const int* __restrict__ csr_src,
                                             const float* __restrict__ dinv,
                                             const float* __restrict__ bias,
                                             float* __restrict__ feat) {
  int tid = threadIdx.x;
  int lane = tid & 63;
  int wv = tid >> 6;
  int node = blockIdx.x * 4 + wv;
  int eslot = lane >> 4;    // 0..3
  int ch16 = lane & 15;     // float4 slot within 64-ch row
  int r0 = row_start[node];
  int r1 = row_start[node + 1];
  float4 a0 = {0.f, 0.f, 0.f, 0.f}, a1 = a0, a2 = a0, a3 = a0;
  float4 a4 = a0, a5 = a0, a6 = a0, a7 = a0;
  int e = r0 + eslot;
  for (; e + 28 < r1; e += 32) {
    int s0 = csr_src[e];
    int s1 = csr_src[e + 4];
    int s2 = csr_src[e + 8];
    int s3 = csr_src[e + 12];
    int s4 = csr_src[e + 16];
    int s5 = csr_src[e + 20];
    int s6 = csr_src[e + 24];
    int s7 = csr_src[e + 28];
    float4 v0 = *(const float4*)(hs + (size_t)s0 * 64 + ch16 * 4);
    float4 v1 = *(const float4*)(hs + (size_t)s1 * 64 + ch16 * 4);
    float4 v2 = *(const float4*)(hs + (size_t)s2 * 64 + ch16 * 4);
    float4 v3 = *(const float4*)(hs + (size_t)s3 * 64 + ch16 * 4);
    float4 v4 = *(const float4*)(hs + (size_t)s4 * 64 + ch16 * 4);
    float4 v5 = *(const float4*)(hs + (size_t)s5 * 64 + ch16 * 4);
    float4 v6 = *(const float4*)(hs + (size_t)s6 * 64 + ch16 * 4);
    float4 v7 = *(const float4*)(hs + (size_t)s7 * 64 + ch16 * 4);
    a0.x += v0.x; a0.y += v0.y; a0.z += v0.z; a0.w += v0.w;
    a1.x += v1.x; a1.y += v1.y; a1.z += v1.z; a1.w += v1.w;
    a2.x += v2.x; a2.y += v2.y; a2.z += v2.z; a2.w += v2.w;
    a3.x += v3.x; a3.y += v3.y; a3.z += v3.z; a3.w += v3.w;
    a4.x += v4.x; a4.y += v4.y; a4.z += v4.z; a4.w += v4.w;
    a5.x += v5.x; a5.y += v5.y; a5.z += v5.z; a5.w += v5.w;
    a6.x += v6.x; a6.y += v6.y; a6.z += v6.z; a6.w += v6.w;
    a7.x += v7.x; a7.y += v7.y; a7.z += v7.z; a7.w += v7.w;
  }
  if (e + 12 < r1) {
    int s0 = csr_src[e];
    int s1 = csr_src[e + 4];
    int s2 = csr_src[e + 8];
    int s3 = csr_src[e + 12];
    float4 v0 = *(const float4*)(hs + (size_t)s0 * 64 + ch16 * 4);
    float4 v1 = *(const float4*)(hs + (size_t)s1 * 64 + ch16 * 4);
    float4 v2 = *(const float4*)(hs + (size_t)s2 * 64 + ch16 * 4);
    float4 v3 = *(const float4*)(hs + (size_t)s3 * 64 + ch16 * 4);
    a0.x += v0.x; a0.y += v0.y; a0.z += v0.z; a0.w += v0.w;
    a1.x += v1.x; a1.y += v1.y; a1.z += v1.z; a1.w += v1.w;
    a2.x += v2.x; a2.y += v2.y; a2.z += v2.z; a2.w += v2.w;
    a3.x += v3.x; a3.y += v3.y; a3.z += v3.z; a3.w += v3.w;
    e += 16;
  }
  for (; e < r1; e += 4) {
    int s = csr_src[e];
    float4 v = *(const float4*)(hs + (size_t)s * 64 + ch16 * 4);
    a0.x += v.x; a0.y += v.y; a0.z += v.z; a0.w += v.w;
  }
  float4 v;
  v.x = ((a0.x + a1.x) + (a2.x + a3.x)) + ((a4.x + a5.x) + (a6.x + a7.x));
  v.y = ((a0.y + a1.y) + (a2.y + a3.y)) + ((a4.y + a5.y) + (a6.y + a7.y));
  v.z = ((a0.z + a1.z) + (a2.z + a3.z)) + ((a4.z + a5.z) + (a6.z + a7.z));
  v.w = ((a0.w + a1.w) + (a2.w + a3.w)) + ((a4.w + a5.w) + (a6.w + a7.w));
#pragma unroll
  for (int off = 16; off <= 32; off <<= 1) {
    v.x += __shfl_xor(v.x, off, 64);
    v.y += __shfl_xor(v.y, off, 64);
    v.z += __shfl_xor(v.z, off, 64);
    v.w += __shfl_xor(v.w, off, 64);
  }
  if (lane < 16) {
    float4 self = *(const float4*)(hs + (size_t)node * 64 + ch16 * 4);
    float4 bb = *(const float4*)(bias + ch16 * 4);
    float dn = dinv[node];
    float4 t, o;
    t.x = dn * (v.x + self.x) + bb.x;
    t.y = dn * (v.y + self.y) + bb.y;
    t.z = dn * (v.z + self.z) + bb.z;
    t.w = dn * (v.w + self.w) + bb.w;
    float4 lt;
    lt.x = (t.x >= 0.f) ? t.x : NEG_SLOPE * t.x;
    lt.y = (t.y >= 0.f) ? t.y : NEG_SLOPE * t.y;
    lt.z = (t.z >= 0.f) ? t.z : NEG_SLOPE * t.z;
    lt.w = (t.w >= 0.f) ? t.w : NEG_SLOPE * t.w;
    if (MODE) {
      o.x = lt.x + t.x; o.y = lt.y + t.y; o.z = lt.z + t.z; o.w = lt.w + t.w;
    } else {
      o = lt;
    }
    *(float4*)(feat + (size_t)node * 64 + ch16 * 4) = o;
  }
}

// ---------------- output head (64 -> 1) ----------------

__global__ __launch_bounds__(256) void k_out_xform(const float* __restrict__ feat,
                                                   const float* __restrict__ W_out,
                                                   const float* __restrict__ dinv,
                                                   float* __restrict__ hs1) {
  int lane = threadIdx.x & 63;
  int w = threadIdx.x >> 6;
  int node = blockIdx.x * 4 + w;
  float v = feat[(size_t)node * 64 + lane] * W_out[lane];
#pragma unroll
  for (int off = 32; off; off >>= 1) v += __shfl_xor(v, off, 64);
  if (lane == 0) hs1[node] = v * dinv[node];
}

__global__ __launch_bounds__(256) void k_out_agg(const float* __restrict__ hs1,
                                                 const int* __restrict__ row_start,
                                                 const int* __restrict__ csr_src,
                                                 const float* __restrict__ dinv,
                                                 const float* __restrict__ b_out,
                                                 float* __restrict__ g) {
  int lane = threadIdx.x & 63;
  int w = threadIdx.x >> 6;
  int node = blockIdx.x * 4 + w;
  int r0 = row_start[node];
  int r1 = row_start[node + 1];
  float acc = 0.f;
  for (int e = r0 + lane; e < r1; e += 64) acc += hs1[csr_src[e]];
#pragma unroll
  for (int off = 32; off; off >>= 1) acc += __shfl_xor(acc, off, 64);
  if (lane == 0) {
    float t = dinv[node] * (acc + hs1[node]) + b_out[0];
    g[node] = (t >= 0.f) ? t : NEG_SLOPE * t;
  }
}

// ---------------- FC head ----------------

__global__ __launch_bounds__(128) void k_fc1(const float* __restrict__ g,
                                             const float* __restrict__ fc1_W,
                                             float* __restrict__ h128) {
  int j = threadIdx.x;  // 0..127
  int base = blockIdx.x * 32;
  int end = base + 32;
  if (end > N_NODES) end = N_NODES;
  float acc = 0.f;
  int i = base;
  for (; i + 4 <= end; i += 4) {
    acc += g[i + 0] * fc1_W[(size_t)(i + 0) * 128 + j];
    acc += g[i + 1] * fc1_W[(size_t)(i + 1) * 128 + j];
    acc += g[i + 2] * fc1_W[(size_t)(i + 2) * 128 + j];
    acc += g[i + 3] * fc1_W[(size_t)(i + 3) * 128 + j];
  }
  for (; i < end; i++) acc += g[i] * fc1_W[(size_t)i * 128 + j];
  atomicAdd(&h128[j], acc);
}

__global__ __launch_bounds__(256) void k_fc2(const float* __restrict__ h128raw,
                                             const float* __restrict__ fc1_b,
                                             const float* __restrict__ fc2_W,
                                             const float* __restrict__ fc2_b,
                                             float* __restrict__ out) {
  __shared__ float sh[128];
  int tid = threadIdx.x;
  if (tid < 128) {
    float v = h128raw[tid] + fc1_b[tid];
    sh[tid] = (v > 0.f) ? v : 0.f;
  }
  __syncthreads();
  int p = blockIdx.x * 256 + tid;
  if (p < POI_LEN) {
    float acc = fc2_b[p];
#pragma unroll 8
    for (int j = 0; j < 128; j++) acc += sh[j] * fc2_W[(size_t)j * POI_LEN + p];
    out[p] = (acc > 0.f) ? acc : 0.f;
  }
}

// ---------------- launch ----------------

extern "C" void kernel_launch(void* const* d_in, const int* in_sizes, int n_in,
                              void* d_out, int out_size, void* d_ws, size_t ws_size,
                              hipStream_t stream) {
  const float* x       = (const float*)d_in[0];
  const int*   ei      = (const int*)d_in[1];
  const float* poi_emb = (const float*)d_in[2];
  const float* cat_emb = (const float*)d_in[3];
  const float* W_in    = (const float*)d_in[4];
  const float* b_in    = (const float*)d_in[5];
  const float* gcn_Ws  = (const float*)d_in[6];
  const float* gcn_bs  = (const float*)d_in[7];
  const float* W_out   = (const float*)d_in[8];
  const float* b_out   = (const float*)d_in[9];
  const float* fc1_W   = (const float*)d_in[10];
  const float* fc1_b   = (const float*)d_in[11];
  const float* fc2_W   = (const float*)d_in[12];
  const float* fc2_b   = (const float*)d_in[13];
  const int* src = ei;
  const int* dst = ei + N_EDGES;

  char* p = (char*)d_ws;
  auto take = [&](size_t bytes) {
    char* r = p;
    p += (bytes + 255) & ~(size_t)255;
    return r;
  };
  int*   cnt       = (int*)take((size_t)N_NODES * 4);
  int*   row_start = (int*)take((size_t)(N_NODES + 1) * 4);
  float* dinv      = (float*)take((size_t)N_NODES * 4);
  int*   bcur      = (int*)take((size_t)B1 * 4);
  int*   csr_src   = (int*)take((size_t)N_EDGES * 4);
  float* feat      = (float*)take((size_t)N_NODES * 64 * 4);
  float* hs        = (float*)take((size_t)N_NODES * 64 * 4);
  float* proj_poi  = (float*)take((size_t)POI_LEN * 64 * 4);  // aliased by staging
  float* proj_cat  = (float*)take((size_t)CAT_LEN * 64 * 4);
  float* hs1       = (float*)take((size_t)N_NODES * 4);
  float* g         = (float*)take((size_t)N_NODES * 4);
  float* h128      = (float*)take(128 * 4);
  int*   partial   = (int*)take((size_t)N_CHUNKS * 4);
  int2*  staging   = (int2*)proj_poi;  // both ~9.81 MB
  float* out       = (float*)d_out;

  const int nb4 = N_NODES / 4;            // 9583
  const int nbE = (N_EDGES + 255) / 256;  // 4792

  k_zero<<<N_CHUNKS, 256, 0, stream>>>(cnt, h128);
  k_count<<<nbE, 256, 0, stream>>>(dst, cnt);
  k_scan1<<<N_CHUNKS, 256, 0, stream>>>(cnt, partial, dinv);
  k_scan2<<<1, 256, 0, stream>>>(partial);
  k_scan3<<<N_CHUNKS, 256, 0, stream>>>(cnt, partial, row_start);
  k_binit<<<(B1 + 255) / 256, 256, 0, stream>>>(row_start, bcur);

  // front-end first (proj_poi's region is reused as scatter staging afterwards)
  k_proj<<<(POI_LEN + PROJ_ROWS - 1) / PROJ_ROWS, 256, 0, stream>>>(
      poi_emb, W_in, proj_poi, POI_LEN, POI_DIM);
  k_proj<<<(CAT_LEN + PROJ_ROWS - 1) / PROJ_ROWS, 256, 0, stream>>>(
      cat_emb, W_in + 300 * 64, proj_cat, CAT_LEN, CAT_DIM);
  k_gather<<<nb4, 256, 0, stream>>>(x, proj_poi, proj_cat, W_in, dinv, hs);

  // CSR edge placement (two-level, coalesced writes)
  k_split<<<NSPLIT, 256, 0, stream>>>(src, dst, bcur, staging);
  k_place<<<B1, 256, 0, stream>>>(staging, row_start, csr_src);

  k_agg<0><<<nb4, 256, 0, stream>>>(hs, row_start, csr_src, dinv, b_in, feat);
  for (int l = 0; l < 5; l++) {
    k_xform<<<nb4, 256, 0, stream>>>(feat, gcn_Ws + (size_t)l * 64 * 64, dinv, hs);
    k_agg<1><<<nb4, 256, 0, stream>>>(hs, row_start, csr_src, dinv,
                                      gcn_bs + (size_t)l * 64, feat);
  }

  k_out_xform<<<nb4, 256, 0, stream>>>(feat, W_out, dinv, hs1);
  k_out_agg<<<nb4, 256, 0, stream>>>(hs1, row_start, csr_src, dinv, b_out, g);
  k_fc1<<<(N_NODES + 31) / 32, 128, 0, stream>>>(g, fc1_W, h128);
  k_fc2<<<(POI_LEN + 255) / 256, 256, 0, stream>>>(h128, fc1_b, fc2_W, fc2_b, out);
}

// Round 8
// 614.263 us; speedup vs baseline: 1.3910x; 1.3910x over previous
//
#include <hip/hip_runtime.h>
#include <hip/hip_bf16.h>

#define N_NODES 38332
#define POI_LEN 38333
#define CAT_LEN 400
#define POI_DIM 300
#define CAT_DIM 100
#define N_EDGES (N_NODES * 32)
#define NEG_SLOPE 0.01f
#define N_CHUNKS ((N_NODES + 255) / 256)  // 150
#define B1 ((N_NODES + 127) / 128)        // 300 coarse dst-buckets
#define SPLIT_CHUNK 4096
#define NSPLIT ((N_EDGES + SPLIT_CHUNK - 1) / SPLIT_CHUNK)  // 300
#define PLACE_CAP 8192

__device__ __forceinline__ unsigned short f2bf(float f) {
  unsigned u = __float_as_uint(f);
  u += 0x7fff + ((u >> 16) & 1);  // RNE
  return (unsigned short)(u >> 16);
}
__device__ __forceinline__ float bflo(unsigned u) {
  return __uint_as_float(u << 16);
}
__device__ __forceinline__ float bfhi(unsigned u) {
  return __uint_as_float(u & 0xffff0000u);
}

// ---------------- CSR build ----------------

__global__ void k_zero(int* __restrict__ cnt, float* __restrict__ h128) {
  int i = blockIdx.x * 256 + threadIdx.x;
  if (i < N_NODES) cnt[i] = 0;
  if (i < 128) h128[i] = 0.f;
}

__global__ void k_count(const int* __restrict__ dst, int* __restrict__ cnt) {
  int e = blockIdx.x * 256 + threadIdx.x;
  if (e < N_EDGES) atomicAdd(&cnt[dst[e]], 1);
}

__global__ __launch_bounds__(256) void k_scan1(const int* __restrict__ cnt,
                                               int* __restrict__ partial,
                                               float* __restrict__ dinv) {
  __shared__ int sb[256];
  int tid = threadIdx.x;
  int i = blockIdx.x * 256 + tid;
  int v = (i < N_NODES) ? cnt[i] : 0;
  if (i < N_NODES) dinv[i] = 1.0f / sqrtf((float)(v + 1));  // deg incl self loop
  sb[tid] = v;
  __syncthreads();
  for (int off = 128; off; off >>= 1) {
    if (tid < off) sb[tid] += sb[tid + off];
    __syncthreads();
  }
  if (tid == 0) partial[blockIdx.x] = sb[0];
}

__global__ __launch_bounds__(256) void k_scan2(int* __restrict__ partial) {
  __shared__ int sb[256];
  int tid = threadIdx.x;
  int v = (tid < N_CHUNKS) ? partial[tid] : 0;
  sb[tid] = v;
  __syncthreads();
  for (int off = 1; off < 256; off <<= 1) {
    int t = (tid >= off) ? sb[tid - off] : 0;
    __syncthreads();
    sb[tid] += t;
    __syncthreads();
  }
  if (tid < N_CHUNKS) partial[tid] = sb[tid] - v;  // exclusive
}

__global__ __launch_bounds__(256) void k_scan3(const int* __restrict__ cnt,
                                               const int* __restrict__ partial,
                                               int* __restrict__ row_start) {
  __shared__ int sb[256];
  int tid = threadIdx.x;
  int i = blockIdx.x * 256 + tid;
  int v = (i < N_NODES) ? cnt[i] : 0;
  sb[tid] = v;
  __syncthreads();
  for (int off = 1; off < 256; off <<= 1) {
    int t = (tid >= off) ? sb[tid - off] : 0;
    __syncthreads();
    sb[tid] += t;
    __syncthreads();
  }
  if (i < N_NODES) row_start[i] = partial[blockIdx.x] + sb[tid] - v;
  if (i == N_NODES - 1) row_start[N_NODES] = partial[blockIdx.x] + sb[tid];
}

__global__ void k_binit(const int* __restrict__ row_start, int* __restrict__ bcur) {
  int b = blockIdx.x * 256 + threadIdx.x;
  if (b < B1) bcur[b] = row_start[b * 128];
}

__global__ __launch_bounds__(256) void k_split(const int* __restrict__ src,
                                               const int* __restrict__ dst,
                                               int* __restrict__ bcur,
                                               int2* __restrict__ staging) {
  __shared__ int hist[B1];
  __shared__ int lbase[B1];
  __shared__ int lcur[B1];
  int tid = threadIdx.x;
  int base = blockIdx.x * SPLIT_CHUNK;
  int n = N_EDGES - base;
  if (n > SPLIT_CHUNK) n = SPLIT_CHUNK;
  for (int b = tid; b < B1; b += 256) {
    hist[b] = 0;
    lcur[b] = 0;
  }
  __syncthreads();
  for (int i = tid; i < n; i += 256) atomicAdd(&hist[dst[base + i] >> 7], 1);
  __syncthreads();
  for (int b = tid; b < B1; b += 256) {
    int c = hist[b];
    lbase[b] = c ? atomicAdd(&bcur[b], c) : 0;
  }
  __syncthreads();
  for (int i = tid; i < n; i += 256) {
    int d = dst[base + i];
    int s = src[base + i];
    int b = d >> 7;
    int off = atomicAdd(&lcur[b], 1);
    staging[lbase[b] + off] = make_int2(s, d);
  }
}

__global__ __launch_bounds__(256) void k_place(const int2* __restrict__ staging,
                                               const int* __restrict__ row_start,
                                               int* __restrict__ csr_src) {
  __shared__ int cur[128];
  __shared__ int buf[PLACE_CAP];
  int b = blockIdx.x;
  int d0 = b * 128;
  int d1 = d0 + 128;
  if (d1 > N_NODES) d1 = N_NODES;
  int tid = threadIdx.x;
  int e0 = row_start[d0];
  int e1 = row_start[d1];
  int cnt = e1 - e0;
  if (tid < d1 - d0) cur[tid] = row_start[d0 + tid] - e0;
  __syncthreads();
  for (int i = tid; i < cnt; i += 256) {
    int2 p = staging[e0 + i];
    int pos = atomicAdd(&cur[p.y - d0], 1);
    if (pos < PLACE_CAP) buf[pos] = p.x;
    else csr_src[e0 + pos] = p.x;  // overflow fallback (statistically never)
  }
  __syncthreads();
  for (int i = tid; i < cnt && i < PLACE_CAP; i += 256) csr_src[e0 + i] = buf[i];
}

// ---------------- unified small GEMM: C[M][64] = A[M][K] @ W[K][64] ----------
// 16 rows/block (4/wave), whole-K staged once (single barrier). EPI=0: fp32
// store (proj tables). EPI=1: *dinv[row], bf16 store (hs for aggregation).

template <int EPI, int K>
__global__ __launch_bounds__(256) void k_proj(const float* __restrict__ A,
                                              const float* __restrict__ W,
                                              void* __restrict__ Cout, int M,
                                              const float* __restrict__ dinv) {
  __shared__ float sA[16][K + 4];
  int tid = threadIdx.x;
  int lane = tid & 63;
  int wv = tid >> 6;
  int row0 = blockIdx.x * 16;
  constexpr int NK4 = K / 4;

  for (int idx = tid; idx < 16 * NK4; idx += 256) {
    int r = idx / NK4;
    int k4 = idx - r * NK4;
    int row = row0 + r;
    float4 v = {0.f, 0.f, 0.f, 0.f};
    if (row < M) v = *(const float4*)(A + (size_t)row * K + k4 * 4);
    *(float4*)&sA[r][k4 * 4] = v;
  }
  __syncthreads();

  float acc[4] = {0.f, 0.f, 0.f, 0.f};
#pragma unroll 4
  for (int k4 = 0; k4 < NK4; k4++) {
    int k = k4 * 4;
    float w0 = W[(k + 0) * 64 + lane];
    float w1 = W[(k + 1) * 64 + lane];
    float w2 = W[(k + 2) * 64 + lane];
    float w3 = W[(k + 3) * 64 + lane];
#pragma unroll
    for (int r = 0; r < 4; r++) {
      const float4 f4 = *(const float4*)&sA[wv * 4 + r][k];
      acc[r] += f4.x * w0 + f4.y * w1 + f4.z * w2 + f4.w * w3;
    }
  }
#pragma unroll
  for (int r = 0; r < 4; r++) {
    int row = row0 + wv * 4 + r;
    if (row < M) {
      if (EPI == 0) {
        ((float*)Cout)[(size_t)row * 64 + lane] = acc[r];
      } else {
        ((unsigned short*)Cout)[(size_t)row * 64 + lane] =
            f2bf(acc[r] * dinv[row]);
      }
    }
  }
}

// ---------------- gather + combine -> bf16 hs ----------------

__global__ __launch_bounds__(256) void k_gather(
    const float* __restrict__ x, const float* __restrict__ proj_poi,
    const float* __restrict__ proj_cat, const float* __restrict__ W_in,
    const float* __restrict__ dinv, unsigned short* __restrict__ hs) {
  int lane = threadIdx.x & 63;
  int w = threadIdx.x >> 6;
  int node = blockIdx.x * 4 + w;
  int pid = (int)x[node * 5 + 0];
  int cid = (int)x[node * 5 + 1];
  float x2 = x[node * 5 + 2];
  float x3 = x[node * 5 + 3];
  float x4 = x[node * 5 + 4];
  float v = proj_poi[(size_t)pid * 64 + lane] + proj_cat[(size_t)cid * 64 + lane] +
            x2 * W_in[400 * 64 + lane] + x3 * W_in[401 * 64 + lane] +
            x4 * W_in[402 * 64 + lane];
  hs[(size_t)node * 64 + lane] = f2bf(v * dinv[node]);
}

// ---------------- aggregation: bf16 gathers, fp32 accumulate ----------------
// wave = 1 dst node. lane = eslot(4) x ch16(16); each lane loads uint2 (4 bf16)
// -> one gather instr covers 4 edges x 128B rows = 8 lines; 4 independent
// accumulators -> 32 lines outstanding per wave.

template <int MODE>
__global__ __launch_bounds__(256) void k_agg(const unsigned short* __restrict__ hs,
                                             const int* __restrict__ row_start,
                                             const int* __restrict__ csr_src,
                                             const float* __restrict__ dinv,
                                             const float* __restrict__ bias,
                                             float* __restrict__ feat) {
  int tid = threadIdx.x;
  int lane = tid & 63;
  int wv = tid >> 6;
  int node = blockIdx.x * 4 + wv;
  int eslot = lane >> 4;  // 0..3
  int ch16 = lane & 15;   // 4-channel group within 64-ch row
  int r0 = row_start[node];
  int r1 = row_start[node + 1];
  float4 a0 = {0.f, 0.f, 0.f, 0.f}, a1 = a0, a2 = a0, a3 = a0;
  int e = r0 + eslot;
  for (; e + 12 < r1; e += 16) {
    int s0 = csr_src[e];
    int s1 = csr_src[e + 4];
    int s2 = csr_src[e + 8];
    int s3 = csr_src[e + 12];
    uint2 v0 = *(const uint2*)(hs + (size_t)s0 * 64 + ch16 * 4);
    uint2 v1 = *(const uint2*)(hs + (size_t)s1 * 64 + ch16 * 4);
    uint2 v2 = *(const uint2*)(hs + (size_t)s2 * 64 + ch16 * 4);
    uint2 v3 = *(const uint2*)(hs + (size_t)s3 * 64 + ch16 * 4);
    a0.x += bflo(v0.x); a0.y += bfhi(v0.x); a0.z += bflo(v0.y); a0.w += bfhi(v0.y);
    a1.x += bflo(v1.x); a1.y += bfhi(v1.x); a1.z += bflo(v1.y); a1.w += bfhi(v1.y);
    a2.x += bflo(v2.x); a2.y += bfhi(v2.x); a2.z += bflo(v2.y); a2.w += bfhi(v2.y);
    a3.x += bflo(v3.x); a3.y += bfhi(v3.x); a3.z += bflo(v3.y); a3.w += bfhi(v3.y);
  }
  for (; e < r1; e += 4) {
    int s = csr_src[e];
    uint2 v = *(const uint2*)(hs + (size_t)s * 64 + ch16 * 4);
    a0.x += bflo(v.x); a0.y += bfhi(v.x); a0.z += bflo(v.y); a0.w += bfhi(v.y);
  }
  float4 v;
  v.x = (a0.x + a1.x) + (a2.x + a3.x);
  v.y = (a0.y + a1.y) + (a2.y + a3.y);
  v.z = (a0.z + a1.z) + (a2.z + a3.z);
  v.w = (a0.w + a1.w) + (a2.w + a3.w);
#pragma unroll
  for (int off = 16; off <= 32; off <<= 1) {
    v.x += __shfl_xor(v.x, off, 64);
    v.y += __shfl_xor(v.y, off, 64);
    v.z += __shfl_xor(v.z, off, 64);
    v.w += __shfl_xor(v.w, off, 64);
  }
  if (lane < 16) {
    uint2 sv = *(const uint2*)(hs + (size_t)node * 64 + ch16 * 4);
    float4 bb = *(const float4*)(bias + ch16 * 4);
    float dn = dinv[node];
    float4 t, o;
    t.x = dn * (v.x + bflo(sv.x)) + bb.x;
    t.y = dn * (v.y + bfhi(sv.x)) + bb.y;
    t.z = dn * (v.z + bflo(sv.y)) + bb.z;
    t.w = dn * (v.w + bfhi(sv.y)) + bb.w;
    float4 lt;
    lt.x = (t.x >= 0.f) ? t.x : NEG_SLOPE * t.x;
    lt.y = (t.y >= 0.f) ? t.y : NEG_SLOPE * t.y;
    lt.z = (t.z >= 0.f) ? t.z : NEG_SLOPE * t.z;
    lt.w = (t.w >= 0.f) ? t.w : NEG_SLOPE * t.w;
    if (MODE) {
      o.x = lt.x + t.x; o.y = lt.y + t.y; o.z = lt.z + t.z; o.w = lt.w + t.w;
    } else {
      o = lt;
    }
    *(float4*)(feat + (size_t)node * 64 + ch16 * 4) = o;
  }
}

// ---------------- output head (64 -> 1) ----------------

__global__ __launch_bounds__(256) void k_out_xform(const float* __restrict__ feat,
                                                   const float* __restrict__ W_out,
                                                   const float* __restrict__ dinv,
                                                   float* __restrict__ hs1) {
  int lane = threadIdx.x & 63;
  int w = threadIdx.x >> 6;
  int node = blockIdx.x * 4 + w;
  float v = feat[(size_t)node * 64 + lane] * W_out[lane];
#pragma unroll
  for (int off = 32; off; off >>= 1) v += __shfl_xor(v, off, 64);
  if (lane == 0) hs1[node] = v * dinv[node];
}

__global__ __launch_bounds__(256) void k_out_agg(const float* __restrict__ hs1,
                                                 const int* __restrict__ row_start,
                                                 const int* __restrict__ csr_src,
                                                 const float* __restrict__ dinv,
                                                 const float* __restrict__ b_out,
                                                 float* __restrict__ g) {
  int lane = threadIdx.x & 63;
  int w = threadIdx.x >> 6;
  int node = blockIdx.x * 4 + w;
  int r0 = row_start[node];
  int r1 = row_start[node + 1];
  float acc = 0.f;
  for (int e = r0 + lane; e < r1; e += 64) acc += hs1[csr_src[e]];
#pragma unroll
  for (int off = 32; off; off >>= 1) acc += __shfl_xor(acc, off, 64);
  if (lane == 0) {
    float t = dinv[node] * (acc + hs1[node]) + b_out[0];
    g[node] = (t >= 0.f) ? t : NEG_SLOPE * t;
  }
}

// ---------------- FC head ----------------

__global__ __launch_bounds__(128) void k_fc1(const float* __restrict__ g,
                                             const float* __restrict__ fc1_W,
                                             float* __restrict__ h128) {
  int j = threadIdx.x;  // 0..127
  int base = blockIdx.x * 32;
  int end = base + 32;
  if (end > N_NODES) end = N_NODES;
  float acc = 0.f;
  int i = base;
  for (; i + 4 <= end; i += 4) {
    acc += g[i + 0] * fc1_W[(size_t)(i + 0) * 128 + j];
    acc += g[i + 1] * fc1_W[(size_t)(i + 1) * 128 + j];
    acc += g[i + 2] * fc1_W[(size_t)(i + 2) * 128 + j];
    acc += g[i + 3] * fc1_W[(size_t)(i + 3) * 128 + j];
  }
  for (; i < end; i++) acc += g[i] * fc1_W[(size_t)i * 128 + j];
  atomicAdd(&h128[j], acc);
}

__global__ __launch_bounds__(256) void k_fc2(const float* __restrict__ h128raw,
                                             const float* __restrict__ fc1_b,
                                             const float* __restrict__ fc2_W,
                                             const float* __restrict__ fc2_b,
                                             float* __restrict__ out) {
  __shared__ float sh[128];
  int tid = threadIdx.x;
  if (tid < 128) {
    float v = h128raw[tid] + fc1_b[tid];
    sh[tid] = (v > 0.f) ? v : 0.f;
  }
  __syncthreads();
  int p = blockIdx.x * 256 + tid;
  if (p < POI_LEN) {
    float acc = fc2_b[p];
#pragma unroll 8
    for (int j = 0; j < 128; j++) acc += sh[j] * fc2_W[(size_t)j * POI_LEN + p];
    out[p] = (acc > 0.f) ? acc : 0.f;
  }
}

// ---------------- launch ----------------

extern "C" void kernel_launch(void* const* d_in, const int* in_sizes, int n_in,
                              void* d_out, int out_size, void* d_ws, size_t ws_size,
                              hipStream_t stream) {
  const float* x       = (const float*)d_in[0];
  const int*   ei      = (const int*)d_in[1];
  const float* poi_emb = (const float*)d_in[2];
  const float* cat_emb = (const float*)d_in[3];
  const float* W_in    = (const float*)d_in[4];
  const float* b_in    = (const float*)d_in[5];
  const float* gcn_Ws  = (const float*)d_in[6];
  const float* gcn_bs  = (const float*)d_in[7];
  const float* W_out   = (const float*)d_in[8];
  const float* b_out   = (const float*)d_in[9];
  const float* fc1_W   = (const float*)d_in[10];
  const float* fc1_b   = (const float*)d_in[11];
  const float* fc2_W   = (const float*)d_in[12];
  const float* fc2_b   = (const float*)d_in[13];
  const int* src = ei;
  const int* dst = ei + N_EDGES;

  char* p = (char*)d_ws;
  auto take = [&](size_t bytes) {
    char* r = p;
    p += (bytes + 255) & ~(size_t)255;
    return r;
  };
  int*   cnt       = (int*)take((size_t)N_NODES * 4);
  int*   row_start = (int*)take((size_t)(N_NODES + 1) * 4);
  float* dinv      = (float*)take((size_t)N_NODES * 4);
  int*   bcur      = (int*)take((size_t)B1 * 4);
  int*   csr_src   = (int*)take((size_t)N_EDGES * 4);
  float* feat      = (float*)take((size_t)N_NODES * 64 * 4);
  unsigned short* hs = (unsigned short*)take((size_t)N_NODES * 64 * 2);
  float* proj_poi  = (float*)take((size_t)POI_LEN * 64 * 4);  // aliased by staging
  float* proj_cat  = (float*)take((size_t)CAT_LEN * 64 * 4);
  float* hs1       = (float*)take((size_t)N_NODES * 4);
  float* g         = (float*)take((size_t)N_NODES * 4);
  float* h128      = (float*)take(128 * 4);
  int*   partial   = (int*)take((size_t)N_CHUNKS * 4);
  int2*  staging   = (int2*)proj_poi;  // both ~9.81 MB
  float* out       = (float*)d_out;

  const int nb4 = N_NODES / 4;            // 9583
  const int nb16 = (N_NODES + 15) / 16;   // 2396
  const int nbE = (N_EDGES + 255) / 256;  // 4792

  k_zero<<<N_CHUNKS, 256, 0, stream>>>(cnt, h128);
  k_count<<<nbE, 256, 0, stream>>>(dst, cnt);
  k_scan1<<<N_CHUNKS, 256, 0, stream>>>(cnt, partial, dinv);
  k_scan2<<<1, 256, 0, stream>>>(partial);
  k_scan3<<<N_CHUNKS, 256, 0, stream>>>(cnt, partial, row_start);
  k_binit<<<(B1 + 255) / 256, 256, 0, stream>>>(row_start, bcur);

  // front-end first (proj_poi's region is reused as scatter staging afterwards)
  k_proj<0, POI_DIM><<<(POI_LEN + 15) / 16, 256, 0, stream>>>(
      poi_emb, W_in, proj_poi, POI_LEN, nullptr);
  k_proj<0, CAT_DIM><<<(CAT_LEN + 15) / 16, 256, 0, stream>>>(
      cat_emb, W_in + 300 * 64, proj_cat, CAT_LEN, nullptr);
  k_gather<<<nb4, 256, 0, stream>>>(x, proj_poi, proj_cat, W_in, dinv, hs);

  // CSR edge placement (two-level, coalesced writes)
  k_split<<<NSPLIT, 256, 0, stream>>>(src, dst, bcur, staging);
  k_place<<<B1, 256, 0, stream>>>(staging, row_start, csr_src);

  k_agg<0><<<nb4, 256, 0, stream>>>(hs, row_start, csr_src, dinv, b_in, feat);
  for (int l = 0; l < 5; l++) {
    k_proj<1, 64><<<nb16, 256, 0, stream>>>(feat, gcn_Ws + (size_t)l * 64 * 64,
                                            hs, N_NODES, dinv);
    k_agg<1><<<nb4, 256, 0, stream>>>(hs, row_start, csr_src, dinv,
                                      gcn_bs + (size_t)l * 64, feat);
  }

  k_out_xform<<<nb4, 256, 0, stream>>>(feat, W_out, dinv, hs1);
  k_out_agg<<<nb4, 256, 0, stream>>>(hs1, row_start, csr_src, dinv, b_out, g);
  k_fc1<<<(N_NODES + 31) / 32, 128, 0, stream>>>(g, fc1_W, h128);
  k_fc2<<<(POI_LEN + 255) / 256, 256, 0, stream>>>(h128, fc1_b, fc2_W, fc2_b, out);
}

// Round 9
// 542.589 us; speedup vs baseline: 1.5748x; 1.1321x over previous
//
#include <hip/hip_runtime.h>
#include <hip/hip_bf16.h>

#define N_NODES 38332
#define POI_LEN 38333
#define CAT_LEN 400
#define POI_DIM 300
#define CAT_DIM 100
#define N_EDGES (N_NODES * 32)
#define NEG_SLOPE 0.01f
#define N_CHUNKS ((N_NODES + 255) / 256)  // 150
#define B1 ((N_NODES + 127) / 128)        // 300 coarse dst-buckets
#define SPLIT_CHUNK 4096
#define NSPLIT ((N_EDGES + SPLIT_CHUNK - 1) / SPLIT_CHUNK)  // 300
#define PLACE_CAP 8192

typedef __attribute__((ext_vector_type(8))) short short8;
typedef __attribute__((ext_vector_type(4))) float f32x4;

__device__ __forceinline__ unsigned short f2bf(float f) {
  unsigned u = __float_as_uint(f);
  u += 0x7fff + ((u >> 16) & 1);  // RNE
  return (unsigned short)(u >> 16);
}
__device__ __forceinline__ float bflo(unsigned u) {
  return __uint_as_float(u << 16);
}
__device__ __forceinline__ float bfhi(unsigned u) {
  return __uint_as_float(u & 0xffff0000u);
}

// ---------------- CSR build ----------------

__global__ void k_zero(int* __restrict__ cnt, float* __restrict__ h128) {
  int i = blockIdx.x * 256 + threadIdx.x;
  if (i < N_NODES) cnt[i] = 0;
  if (i < 128) h128[i] = 0.f;
}

__global__ void k_count(const int* __restrict__ dst, int* __restrict__ cnt) {
  int e = blockIdx.x * 256 + threadIdx.x;
  if (e < N_EDGES) atomicAdd(&cnt[dst[e]], 1);
}

__global__ __launch_bounds__(256) void k_scan1(const int* __restrict__ cnt,
                                               int* __restrict__ partial,
                                               float* __restrict__ dinv) {
  __shared__ int sb[256];
  int tid = threadIdx.x;
  int i = blockIdx.x * 256 + tid;
  int v = (i < N_NODES) ? cnt[i] : 0;
  if (i < N_NODES) dinv[i] = 1.0f / sqrtf((float)(v + 1));  // deg incl self loop
  sb[tid] = v;
  __syncthreads();
  for (int off = 128; off; off >>= 1) {
    if (tid < off) sb[tid] += sb[tid + off];
    __syncthreads();
  }
  if (tid == 0) partial[blockIdx.x] = sb[0];
}

__global__ __launch_bounds__(256) void k_scan2(int* __restrict__ partial) {
  __shared__ int sb[256];
  int tid = threadIdx.x;
  int v = (tid < N_CHUNKS) ? partial[tid] : 0;
  sb[tid] = v;
  __syncthreads();
  for (int off = 1; off < 256; off <<= 1) {
    int t = (tid >= off) ? sb[tid - off] : 0;
    __syncthreads();
    sb[tid] += t;
    __syncthreads();
  }
  if (tid < N_CHUNKS) partial[tid] = sb[tid] - v;  // exclusive
}

__global__ __launch_bounds__(256) void k_scan3(const int* __restrict__ cnt,
                                               const int* __restrict__ partial,
                                               int* __restrict__ row_start) {
  __shared__ int sb[256];
  int tid = threadIdx.x;
  int i = blockIdx.x * 256 + tid;
  int v = (i < N_NODES) ? cnt[i] : 0;
  sb[tid] = v;
  __syncthreads();
  for (int off = 1; off < 256; off <<= 1) {
    int t = (tid >= off) ? sb[tid - off] : 0;
    __syncthreads();
    sb[tid] += t;
    __syncthreads();
  }
  if (i < N_NODES) row_start[i] = partial[blockIdx.x] + sb[tid] - v;
  if (i == N_NODES - 1) row_start[N_NODES] = partial[blockIdx.x] + sb[tid];
}

__global__ void k_binit(const int* __restrict__ row_start, int* __restrict__ bcur) {
  int b = blockIdx.x * 256 + threadIdx.x;
  if (b < B1) bcur[b] = row_start[b * 128];
}

__global__ __launch_bounds__(256) void k_split(const int* __restrict__ src,
                                               const int* __restrict__ dst,
                                               int* __restrict__ bcur,
                                               int2* __restrict__ staging) {
  __shared__ int hist[B1];
  __shared__ int lbase[B1];
  __shared__ int lcur[B1];
  int tid = threadIdx.x;
  int base = blockIdx.x * SPLIT_CHUNK;
  int n = N_EDGES - base;
  if (n > SPLIT_CHUNK) n = SPLIT_CHUNK;
  for (int b = tid; b < B1; b += 256) {
    hist[b] = 0;
    lcur[b] = 0;
  }
  __syncthreads();
  for (int i = tid; i < n; i += 256) atomicAdd(&hist[dst[base + i] >> 7], 1);
  __syncthreads();
  for (int b = tid; b < B1; b += 256) {
    int c = hist[b];
    lbase[b] = c ? atomicAdd(&bcur[b], c) : 0;
  }
  __syncthreads();
  for (int i = tid; i < n; i += 256) {
    int d = dst[base + i];
    int s = src[base + i];
    int b = d >> 7;
    int off = atomicAdd(&lcur[b], 1);
    staging[lbase[b] + off] = make_int2(s, d);
  }
}

__global__ __launch_bounds__(256) void k_place(const int2* __restrict__ staging,
                                               const int* __restrict__ row_start,
                                               int* __restrict__ csr_src) {
  __shared__ int cur[128];
  __shared__ int buf[PLACE_CAP];
  int b = blockIdx.x;
  int d0 = b * 128;
  int d1 = d0 + 128;
  if (d1 > N_NODES) d1 = N_NODES;
  int tid = threadIdx.x;
  int e0 = row_start[d0];
  int e1 = row_start[d1];
  int cnt = e1 - e0;
  if (tid < d1 - d0) cur[tid] = row_start[d0 + tid] - e0;
  __syncthreads();
  for (int i = tid; i < cnt; i += 256) {
    int2 p = staging[e0 + i];
    int pos = atomicAdd(&cur[p.y - d0], 1);
    if (pos < PLACE_CAP) buf[pos] = p.x;
    else csr_src[e0 + pos] = p.x;  // overflow fallback (statistically never)
  }
  __syncthreads();
  for (int i = tid; i < cnt && i < PLACE_CAP; i += 256) csr_src[e0 + i] = buf[i];
}

// ---------------- W pre-swizzle into B-fragment order (bf16) --------------
// Wf[((ks*4 + quad)*64 + n)*8 + j] = bf16(W[ks*32 + quad*8 + j][n]), 0-pad k>=K.

__global__ void k_wswz(const float* __restrict__ W, int K, int total,
                       unsigned short* __restrict__ Wf) {
  int idx = blockIdx.x * 256 + threadIdx.x;
  if (idx >= total) return;
  int j = idx & 7;
  int n = (idx >> 3) & 63;
  int q = (idx >> 9) & 3;
  int ks = idx >> 11;
  int k = ks * 32 + q * 8 + j;
  float v = (k < K) ? W[k * 64 + n] : 0.f;
  Wf[idx] = f2bf(v);
}

// ---------------- MFMA GEMM: C[M][64] = A[M][K] @ W[K][64] ----------------
// 16 rows/block; wave wv computes cols [16wv,16wv+16) via mfma_f32_16x16x32_bf16.
// A staged to LDS as bf16; B-frag = one coalesced 16B global load per K-step.
// Fragment layouts (HW-verified, learn_hip m89/m120): A[m=lane&15][k=quad*8+j],
// B[k=quad*8+j][n=lane&15], C[row=quad*4+reg][col=lane&15].
// EPI=0: fp32 store (proj tables). EPI=1: *dinv[row], bf16 store (hs).

template <int EPI, int K, int K_pad>
__global__ __launch_bounds__(256) void k_projm(const float* __restrict__ A,
                                               const unsigned short* __restrict__ Wf,
                                               void* __restrict__ Cout, int M,
                                               const float* __restrict__ dinv) {
  constexpr int RS = K_pad + 8;  // LDS row stride (ushorts), keeps 16B align
  __shared__ unsigned short sA[16 * RS];
  __shared__ float sC[16 * 68];
  int tid = threadIdx.x;
  int lane = tid & 63;
  int wv = tid >> 6;
  int row0 = blockIdx.x * 16;

  // stage A -> bf16 LDS (zeros for pad region / tail rows)
  constexpr int NKP4 = K_pad / 4;
  for (int idx = tid; idx < 16 * NKP4; idx += 256) {
    int r = idx / NKP4;
    int k = (idx - r * NKP4) * 4;
    int row = row0 + r;
    ushort4 o = {0, 0, 0, 0};
    if (row < M && k < K) {  // K%4==0 so full float4 in range
      float4 f = *(const float4*)(A + (size_t)row * K + k);
      o.x = f2bf(f.x); o.y = f2bf(f.y); o.z = f2bf(f.z); o.w = f2bf(f.w);
    }
    *(ushort4*)&sA[r * RS + k] = o;
  }
  __syncthreads();

  int c = lane & 15;
  int q = lane >> 4;
  int n0 = wv * 16;
  f32x4 acc = {0.f, 0.f, 0.f, 0.f};
  const unsigned short* arow = &sA[c * RS];
#pragma unroll
  for (int ks = 0; ks < K_pad / 32; ks++) {
    short8 af = *(const short8*)(arow + ks * 32 + q * 8);
    short8 bf = *(const short8*)(Wf + ((size_t)((ks * 4 + q) * 64 + n0 + c)) * 8);
    acc = __builtin_amdgcn_mfma_f32_16x16x32_bf16(af, bf, acc, 0, 0, 0);
  }
#pragma unroll
  for (int r = 0; r < 4; r++) sC[(q * 4 + r) * 68 + n0 + c] = acc[r];
  __syncthreads();

  for (int idx = tid; idx < 16 * 64; idx += 256) {
    int r = idx >> 6, col = idx & 63;
    int row = row0 + r;
    if (row < M) {
      float v = sC[r * 68 + col];
      if (EPI == 0) {
        ((float*)Cout)[(size_t)row * 64 + col] = v;
      } else {
        ((unsigned short*)Cout)[(size_t)row * 64 + col] = f2bf(v * dinv[row]);
      }
    }
  }
}

// ---------------- gather + combine -> bf16 hs ----------------

__global__ __launch_bounds__(256) void k_gather(
    const float* __restrict__ x, const float* __restrict__ proj_poi,
    const float* __restrict__ proj_cat, const float* __restrict__ W_in,
    const float* __restrict__ dinv, unsigned short* __restrict__ hs) {
  int lane = threadIdx.x & 63;
  int w = threadIdx.x >> 6;
  int node = blockIdx.x * 4 + w;
  int pid = (int)x[node * 5 + 0];
  int cid = (int)x[node * 5 + 1];
  float x2 = x[node * 5 + 2];
  float x3 = x[node * 5 + 3];
  float x4 = x[node * 5 + 4];
  float v = proj_poi[(size_t)pid * 64 + lane] + proj_cat[(size_t)cid * 64 + lane] +
            x2 * W_in[400 * 64 + lane] + x3 * W_in[401 * 64 + lane] +
            x4 * W_in[402 * 64 + lane];
  hs[(size_t)node * 64 + lane] = f2bf(v * dinv[node]);
}

// ---------------- aggregation: bf16 gathers, fp32 accumulate ----------------

template <int MODE>
__global__ __launch_bounds__(256) void k_agg(const unsigned short* __restrict__ hs,
                                             const int* __restrict__ row_start,
                                             const int* __restrict__ csr_src,
                                             const float* __restrict__ dinv,
                                             const float* __restrict__ bias,
                                             float* __restrict__ feat) {
  int tid = threadIdx.x;
  int lane = tid & 63;
  int wv = tid >> 6;
  int node = blockIdx.x * 4 + wv;
  int eslot = lane >> 4;  // 0..3
  int ch16 = lane & 15;   // 4-channel group within 64-ch row
  int r0 = row_start[node];
  int r1 = row_start[node + 1];
  float4 a0 = {0.f, 0.f, 0.f, 0.f}, a1 = a0, a2 = a0, a3 = a0;
  int e = r0 + eslot;
  for (; e + 12 < r1; e += 16) {
    int s0 = csr_src[e];
    int s1 = csr_src[e + 4];
    int s2 = csr_src[e + 8];
    int s3 = csr_src[e + 12];
    uint2 v0 = *(const uint2*)(hs + (size_t)s0 * 64 + ch16 * 4);
    uint2 v1 = *(const uint2*)(hs + (size_t)s1 * 64 + ch16 * 4);
    uint2 v2 = *(const uint2*)(hs + (size_t)s2 * 64 + ch16 * 4);
    uint2 v3 = *(const uint2*)(hs + (size_t)s3 * 64 + ch16 * 4);
    a0.x += bflo(v0.x); a0.y += bfhi(v0.x); a0.z += bflo(v0.y); a0.w += bfhi(v0.y);
    a1.x += bflo(v1.x); a1.y += bfhi(v1.x); a1.z += bflo(v1.y); a1.w += bfhi(v1.y);
    a2.x += bflo(v2.x); a2.y += bfhi(v2.x); a2.z += bflo(v2.y); a2.w += bfhi(v2.y);
    a3.x += bflo(v3.x); a3.y += bfhi(v3.x); a3.z += bflo(v3.y); a3.w += bfhi(v3.y);
  }
  for (; e < r1; e += 4) {
    int s = csr_src[e];
    uint2 v = *(const uint2*)(hs + (size_t)s * 64 + ch16 * 4);
    a0.x += bflo(v.x); a0.y += bfhi(v.x); a0.z += bflo(v.y); a0.w += bfhi(v.y);
  }
  float4 v;
  v.x = (a0.x + a1.x) + (a2.x + a3.x);
  v.y = (a0.y + a1.y) + (a2.y + a3.y);
  v.z = (a0.z + a1.z) + (a2.z + a3.z);
  v.w = (a0.w + a1.w) + (a2.w + a3.w);
#pragma unroll
  for (int off = 16; off <= 32; off <<= 1) {
    v.x += __shfl_xor(v.x, off, 64);
    v.y += __shfl_xor(v.y, off, 64);
    v.z += __shfl_xor(v.z, off, 64);
    v.w += __shfl_xor(v.w, off, 64);
  }
  if (lane < 16) {
    uint2 sv = *(const uint2*)(hs + (size_t)node * 64 + ch16 * 4);
    float4 bb = *(const float4*)(bias + ch16 * 4);
    float dn = dinv[node];
    float4 t, o;
    t.x = dn * (v.x + bflo(sv.x)) + bb.x;
    t.y = dn * (v.y + bfhi(sv.x)) + bb.y;
    t.z = dn * (v.z + bflo(sv.y)) + bb.z;
    t.w = dn * (v.w + bfhi(sv.y)) + bb.w;
    float4 lt;
    lt.x = (t.x >= 0.f) ? t.x : NEG_SLOPE * t.x;
    lt.y = (t.y >= 0.f) ? t.y : NEG_SLOPE * t.y;
    lt.z = (t.z >= 0.f) ? t.z : NEG_SLOPE * t.z;
    lt.w = (t.w >= 0.f) ? t.w : NEG_SLOPE * t.w;
    if (MODE) {
      o.x = lt.x + t.x; o.y = lt.y + t.y; o.z = lt.z + t.z; o.w = lt.w + t.w;
    } else {
      o = lt;
    }
    *(float4*)(feat + (size_t)node * 64 + ch16 * 4) = o;
  }
}

// ---------------- output head (64 -> 1) ----------------

__global__ __launch_bounds__(256) void k_out_xform(const float* __restrict__ feat,
                                                   const float* __restrict__ W_out,
                                                   const float* __restrict__ dinv,
                                                   float* __restrict__ hs1) {
  int lane = threadIdx.x & 63;
  int w = threadIdx.x >> 6;
  int node = blockIdx.x * 4 + w;
  float v = feat[(size_t)node * 64 + lane] * W_out[lane];
#pragma unroll
  for (int off = 32; off; off >>= 1) v += __shfl_xor(v, off, 64);
  if (lane == 0) hs1[node] = v * dinv[node];
}

__global__ __launch_bounds__(256) void k_out_agg(const float* __restrict__ hs1,
                                                 const int* __restrict__ row_start,
                                                 const int* __restrict__ csr_src,
                                                 const float* __restrict__ dinv,
                                                 const float* __restrict__ b_out,
                                                 float* __restrict__ g) {
  int lane = threadIdx.x & 63;
  int w = threadIdx.x >> 6;
  int node = blockIdx.x * 4 + w;
  int r0 = row_start[node];
  int r1 = row_start[node + 1];
  float acc = 0.f;
  for (int e = r0 + lane; e < r1; e += 64) acc += hs1[csr_src[e]];
#pragma unroll
  for (int off = 32; off; off >>= 1) acc += __shfl_xor(acc, off, 64);
  if (lane == 0) {
    float t = dinv[node] * (acc + hs1[node]) + b_out[0];
    g[node] = (t >= 0.f) ? t : NEG_SLOPE * t;
  }
}

// ---------------- FC head ----------------

__global__ __launch_bounds__(128) void k_fc1(const float* __restrict__ g,
                                             const float* __restrict__ fc1_W,
                                             float* __restrict__ h128) {
  int j = threadIdx.x;  // 0..127
  int base = blockIdx.x * 32;
  int end = base + 32;
  if (end > N_NODES) end = N_NODES;
  float acc = 0.f;
  int i = base;
  for (; i + 4 <= end; i += 4) {
    acc += g[i + 0] * fc1_W[(size_t)(i + 0) * 128 + j];
    acc += g[i + 1] * fc1_W[(size_t)(i + 1) * 128 + j];
    acc += g[i + 2] * fc1_W[(size_t)(i + 2) * 128 + j];
    acc += g[i + 3] * fc1_W[(size_t)(i + 3) * 128 + j];
  }
  for (; i < end; i++) acc += g[i] * fc1_W[(size_t)i * 128 + j];
  atomicAdd(&h128[j], acc);
}

__global__ __launch_bounds__(256) void k_fc2(const float* __restrict__ h128raw,
                                             const float* __restrict__ fc1_b,
                                             const float* __restrict__ fc2_W,
                                             const float* __restrict__ fc2_b,
                                             float* __restrict__ out) {
  __shared__ float sh[128];
  int tid = threadIdx.x;
  if (tid < 128) {
    float v = h128raw[tid] + fc1_b[tid];
    sh[tid] = (v > 0.f) ? v : 0.f;
  }
  __syncthreads();
  int p = blockIdx.x * 256 + tid;
  if (p < POI_LEN) {
    float acc = fc2_b[p];
#pragma unroll 8
    for (int j = 0; j < 128; j++) acc += sh[j] * fc2_W[(size_t)j * POI_LEN + p];
    out[p] = (acc > 0.f) ? acc : 0.f;
  }
}

// ---------------- launch ----------------

extern "C" void kernel_launch(void* const* d_in, const int* in_sizes, int n_in,
                              void* d_out, int out_size, void* d_ws, size_t ws_size,
                              hipStream_t stream) {
  const float* x       = (const float*)d_in[0];
  const int*   ei      = (const int*)d_in[1];
  const float* poi_emb = (const float*)d_in[2];
  const float* cat_emb = (const float*)d_in[3];
  const float* W_in    = (const float*)d_in[4];
  const float* b_in    = (const float*)d_in[5];
  const float* gcn_Ws  = (const float*)d_in[6];
  const float* gcn_bs  = (const float*)d_in[7];
  const float* W_out   = (const float*)d_in[8];
  const float* b_out   = (const float*)d_in[9];
  const float* fc1_W   = (const float*)d_in[10];
  const float* fc1_b   = (const float*)d_in[11];
  const float* fc2_W   = (const float*)d_in[12];
  const float* fc2_b   = (const float*)d_in[13];
  const int* src = ei;
  const int* dst = ei + N_EDGES;

  char* p = (char*)d_ws;
  auto take = [&](size_t bytes) {
    char* r = p;
    p += (bytes + 255) & ~(size_t)255;
    return r;
  };
  int*   cnt       = (int*)take((size_t)N_NODES * 4);
  int*   row_start = (int*)take((size_t)(N_NODES + 1) * 4);
  float* dinv      = (float*)take((size_t)N_NODES * 4);
  int*   bcur      = (int*)take((size_t)B1 * 4);
  int*   csr_src   = (int*)take((size_t)N_EDGES * 4);
  float* feat      = (float*)take((size_t)N_NODES * 64 * 4);
  unsigned short* hs = (unsigned short*)take((size_t)N_NODES * 64 * 2);
  float* proj_poi  = (float*)take((size_t)POI_LEN * 64 * 4);  // aliased by staging
  float* proj_cat  = (float*)take((size_t)CAT_LEN * 64 * 4);
  float* hs1       = (float*)take((size_t)N_NODES * 4);
  float* g         = (float*)take((size_t)N_NODES * 4);
  float* h128      = (float*)take(128 * 4);
  int*   partial   = (int*)take((size_t)N_CHUNKS * 4);
  unsigned short* wf_poi = (unsigned short*)take((size_t)320 * 64 * 2);
  unsigned short* wf_cat = (unsigned short*)take((size_t)128 * 64 * 2);
  unsigned short* wf_gcn = (unsigned short*)take((size_t)5 * 64 * 64 * 2);
  int2*  staging   = (int2*)proj_poi;  // both ~9.81 MB
  float* out       = (float*)d_out;

  const int nb4 = N_NODES / 4;            // 9583
  const int nb16 = (N_NODES + 15) / 16;   // 2396
  const int nbE = (N_EDGES + 255) / 256;  // 4792

  k_zero<<<N_CHUNKS, 256, 0, stream>>>(cnt, h128);
  k_count<<<nbE, 256, 0, stream>>>(dst, cnt);
  k_scan1<<<N_CHUNKS, 256, 0, stream>>>(cnt, partial, dinv);
  k_scan2<<<1, 256, 0, stream>>>(partial);
  k_scan3<<<N_CHUNKS, 256, 0, stream>>>(cnt, partial, row_start);
  k_binit<<<(B1 + 255) / 256, 256, 0, stream>>>(row_start, bcur);

  // W pre-swizzle (bf16, B-frag order)
  k_wswz<<<(320 * 64 + 255) / 256, 256, 0, stream>>>(W_in, POI_DIM, 320 * 64, wf_poi);
  k_wswz<<<(128 * 64 + 255) / 256, 256, 0, stream>>>(W_in + 300 * 64, CAT_DIM,
                                                     128 * 64, wf_cat);
  for (int l = 0; l < 5; l++)
    k_wswz<<<(64 * 64 + 255) / 256, 256, 0, stream>>>(
        gcn_Ws + (size_t)l * 64 * 64, 64, 64 * 64, wf_gcn + (size_t)l * 64 * 64);

  // front-end (proj_poi's region is reused as scatter staging afterwards)
  k_projm<0, POI_DIM, 320><<<(POI_LEN + 15) / 16, 256, 0, stream>>>(
      poi_emb, wf_poi, proj_poi, POI_LEN, nullptr);
  k_projm<0, CAT_DIM, 128><<<(CAT_LEN + 15) / 16, 256, 0, stream>>>(
      cat_emb, wf_cat, proj_cat, CAT_LEN, nullptr);
  k_gather<<<nb4, 256, 0, stream>>>(x, proj_poi, proj_cat, W_in, dinv, hs);

  // CSR edge placement (two-level, coalesced writes)
  k_split<<<NSPLIT, 256, 0, stream>>>(src, dst, bcur, staging);
  k_place<<<B1, 256, 0, stream>>>(staging, row_start, csr_src);

  k_agg<0><<<nb4, 256, 0, stream>>>(hs, row_start, csr_src, dinv, b_in, feat);
  for (int l = 0; l < 5; l++) {
    k_projm<1, 64, 64><<<nb16, 256, 0, stream>>>(
        feat, wf_gcn + (size_t)l * 64 * 64, hs, N_NODES, dinv);
    k_agg<1><<<nb4, 256, 0, stream>>>(hs, row_start, csr_src, dinv,
                                      gcn_bs + (size_t)l * 64, feat);
  }

  k_out_xform<<<nb4, 256, 0, stream>>>(feat, W_out, dinv, hs1);
  k_out_agg<<<nb4, 256, 0, stream>>>(hs1, row_start, csr_src, dinv, b_out, g);
  k_fc1<<<(N_NODES + 31) / 32, 128, 0, stream>>>(g, fc1_W, h128);
  k_fc2<<<(POI_LEN + 255) / 256, 256, 0, stream>>>(h128, fc1_b, fc2_W, fc2_b, out);
}

// Round 10
// 464.702 us; speedup vs baseline: 1.8387x; 1.1676x over previous
//
#include <hip/hip_runtime.h>
#include <hip/hip_bf16.h>

#define N_NODES 38332
#define POI_LEN 38333
#define CAT_LEN 400
#define POI_DIM 300
#define CAT_DIM 100
#define N_EDGES (N_NODES * 32)
#define NEG_SLOPE 0.01f
#define B1 ((N_NODES + 127) / 128)        // 300 dst-buckets (128 dsts each)
#define SPLIT_CHUNK 4096
#define NSPLIT ((N_EDGES + SPLIT_CHUNK - 1) / SPLIT_CHUNK)  // 300
#define PLACE_CAP 8192
#define BCAP 8192                          // staging capacity per bucket

typedef __attribute__((ext_vector_type(8))) short short8;
typedef __attribute__((ext_vector_type(4))) float f32x4;

__device__ __forceinline__ unsigned short f2bf(float f) {
  unsigned u = __float_as_uint(f);
  u += 0x7fff + ((u >> 16) & 1);  // RNE
  return (unsigned short)(u >> 16);
}
__device__ __forceinline__ float bflo(unsigned u) {
  return __uint_as_float(u << 16);
}
__device__ __forceinline__ float bfhi(unsigned u) {
  return __uint_as_float(u & 0xffff0000u);
}

// ---------------- CSR build (count-free, two-level) ----------------

__global__ void k_zero(int* __restrict__ bcnt, float* __restrict__ h128) {
  int i = blockIdx.x * 256 + threadIdx.x;
  if (i < B1) bcnt[i] = 0;
  if (i < 128) h128[i] = 0.f;
}

// bucket edges by dst>>7 into per-bucket fixed regions; per-(block,bucket)
// global reservation only (90K cheap atomics, no per-edge global atomics).
__global__ __launch_bounds__(256) void k_split(const int* __restrict__ src,
                                               const int* __restrict__ dst,
                                               int* __restrict__ bcnt,
                                               int2* __restrict__ staging) {
  __shared__ int hist[B1];
  __shared__ int lbase[B1];
  __shared__ int lcur[B1];
  int tid = threadIdx.x;
  int base = blockIdx.x * SPLIT_CHUNK;
  int n = N_EDGES - base;
  if (n > SPLIT_CHUNK) n = SPLIT_CHUNK;
  for (int b = tid; b < B1; b += 256) {
    hist[b] = 0;
    lcur[b] = 0;
  }
  __syncthreads();
  for (int i = tid; i < n; i += 256) atomicAdd(&hist[dst[base + i] >> 7], 1);
  __syncthreads();
  for (int b = tid; b < B1; b += 256) {
    int c = hist[b];
    lbase[b] = c ? atomicAdd(&bcnt[b], c) : 0;
  }
  __syncthreads();
  for (int i = tid; i < n; i += 256) {
    int d = dst[base + i];
    int s = src[base + i];
    int b = d >> 7;
    int off = atomicAdd(&lcur[b], 1);
    staging[(size_t)b * BCAP + lbase[b] + off] = make_int2(s, d);
  }
}

// exclusive scan of 300 bucket counts -> bbase[0..300]
__global__ __launch_bounds__(256) void k_bscan(const int* __restrict__ bcnt,
                                               int* __restrict__ bbase) {
  __shared__ int sb[256];
  __shared__ int s_tot;
  int tid = threadIdx.x;
  int running = 0;
  for (int b0 = 0; b0 < B1; b0 += 256) {
    int i = b0 + tid;
    int v = (i < B1) ? bcnt[i] : 0;
    sb[tid] = v;
    __syncthreads();
    for (int off = 1; off < 256; off <<= 1) {
      int t = (tid >= off) ? sb[tid - off] : 0;
      __syncthreads();
      sb[tid] += t;
      __syncthreads();
    }
    if (i < B1) bbase[i] = running + sb[tid] - v;
    if (tid == 255) s_tot = sb[255];
    __syncthreads();
    running += s_tot;
  }
  if (tid == 0) bbase[B1] = running;
}

// per bucket: local histogram + scan -> row_start/dinv, then exact placement
// in LDS and a coalesced CSR copy-out.
__global__ __launch_bounds__(256) void k_place(const int2* __restrict__ staging,
                                               const int* __restrict__ bcnt,
                                               const int* __restrict__ bbase,
                                               int* __restrict__ csr_src,
                                               int* __restrict__ row_start,
                                               float* __restrict__ dinv) {
  __shared__ int lc[128];
  __shared__ int ls[256];
  __shared__ int cur[128];
  __shared__ int buf[PLACE_CAP];
  int b = blockIdx.x;
  int tid = threadIdx.x;
  int d0 = b * 128;
  int nd = N_NODES - d0;
  if (nd > 128) nd = 128;
  int cnt_b = bcnt[b];
  int base = bbase[b];
  const int2* st = staging + (size_t)b * BCAP;
  if (tid < 128) lc[tid] = 0;
  __syncthreads();
  for (int i = tid; i < cnt_b; i += 256) atomicAdd(&lc[st[i].y - d0], 1);
  __syncthreads();
  int v = (tid < 128) ? lc[tid] : 0;
  ls[tid] = v;
  __syncthreads();
  for (int off = 1; off < 128; off <<= 1) {
    int t = (tid >= off) ? ls[tid - off] : 0;
    __syncthreads();
    ls[tid] += t;
    __syncthreads();
  }
  if (tid < 128) {
    int excl = ls[tid] - v;
    cur[tid] = excl;
    if (tid < nd) {
      row_start[d0 + tid] = base + excl;
      dinv[d0 + tid] = 1.0f / sqrtf((float)(v + 1));  // deg incl self loop
    }
  }
  if (b == B1 - 1 && tid == 0) row_start[N_NODES] = base + cnt_b;
  __syncthreads();
  for (int i = tid; i < cnt_b; i += 256) {
    int2 p = st[i];
    int pos = atomicAdd(&cur[p.y - d0], 1);
    buf[pos] = p.x;
  }
  __syncthreads();
  for (int i = tid; i < cnt_b; i += 256) csr_src[base + i] = buf[i];
}

// ---------------- W pre-swizzle into B-fragment order (bf16) --------------

__global__ void k_wswz(const float* __restrict__ W, int K, int total,
                       unsigned short* __restrict__ Wf) {
  int idx = blockIdx.x * 256 + threadIdx.x;
  if (idx >= total) return;
  int j = idx & 7;
  int n = (idx >> 3) & 63;
  int q = (idx >> 9) & 3;
  int ks = idx >> 11;
  int k = ks * 32 + q * 8 + j;
  float v = (k < K) ? W[k * 64 + n] : 0.f;
  Wf[idx] = f2bf(v);
}

// ---------------- MFMA GEMM: C[M][64] = A[M][K] @ W[K][64] ----------------

template <int EPI, int K, int K_pad>
__global__ __launch_bounds__(256) void k_projm(const float* __restrict__ A,
                                               const unsigned short* __restrict__ Wf,
                                               void* __restrict__ Cout, int M,
                                               const float* __restrict__ dinv) {
  constexpr int RS = K_pad + 8;
  __shared__ unsigned short sA[16 * RS];
  __shared__ float sC[16 * 68];
  int tid = threadIdx.x;
  int lane = tid & 63;
  int wv = tid >> 6;
  int row0 = blockIdx.x * 16;

  constexpr int NKP4 = K_pad / 4;
  for (int idx = tid; idx < 16 * NKP4; idx += 256) {
    int r = idx / NKP4;
    int k = (idx - r * NKP4) * 4;
    int row = row0 + r;
    ushort4 o = {0, 0, 0, 0};
    if (row < M && k < K) {
      float4 f = *(const float4*)(A + (size_t)row * K + k);
      o.x = f2bf(f.x); o.y = f2bf(f.y); o.z = f2bf(f.z); o.w = f2bf(f.w);
    }
    *(ushort4*)&sA[r * RS + k] = o;
  }
  __syncthreads();

  int c = lane & 15;
  int q = lane >> 4;
  int n0 = wv * 16;
  f32x4 acc = {0.f, 0.f, 0.f, 0.f};
  const unsigned short* arow = &sA[c * RS];
#pragma unroll
  for (int ks = 0; ks < K_pad / 32; ks++) {
    short8 af = *(const short8*)(arow + ks * 32 + q * 8);
    short8 bf = *(const short8*)(Wf + ((size_t)((ks * 4 + q) * 64 + n0 + c)) * 8);
    acc = __builtin_amdgcn_mfma_f32_16x16x32_bf16(af, bf, acc, 0, 0, 0);
  }
#pragma unroll
  for (int r = 0; r < 4; r++) sC[(q * 4 + r) * 68 + n0 + c] = acc[r];
  __syncthreads();

  for (int idx = tid; idx < 16 * 64; idx += 256) {
    int r = idx >> 6, col = idx & 63;
    int row = row0 + r;
    if (row < M) {
      float v = sC[r * 68 + col];
      if (EPI == 0) {
        ((float*)Cout)[(size_t)row * 64 + col] = v;
      } else {
        ((unsigned short*)Cout)[(size_t)row * 64 + col] = f2bf(v * dinv[row]);
      }
    }
  }
}

// ---------------- gather + combine -> bf16 hs ----------------

__global__ __launch_bounds__(256) void k_gather(
    const float* __restrict__ x, const float* __restrict__ proj_poi,
    const float* __restrict__ proj_cat, const float* __restrict__ W_in,
    const float* __restrict__ dinv, unsigned short* __restrict__ hs) {
  int lane = threadIdx.x & 63;
  int w = threadIdx.x >> 6;
  int node = blockIdx.x * 4 + w;
  int pid = (int)x[node * 5 + 0];
  int cid = (int)x[node * 5 + 1];
  float x2 = x[node * 5 + 2];
  float x3 = x[node * 5 + 3];
  float x4 = x[node * 5 + 4];
  float v = proj_poi[(size_t)pid * 64 + lane] + proj_cat[(size_t)cid * 64 + lane] +
            x2 * W_in[400 * 64 + lane] + x3 * W_in[401 * 64 + lane] +
            x4 * W_in[402 * 64 + lane];
  hs[(size_t)node * 64 + lane] = f2bf(v * dinv[node]);
}

// ---------------- aggregation: uint4 bf16 gathers, fp32 accumulate --------
// wave = 1 dst node. lane = eslot(8) x ch8(8); each lane loads uint4 (8 bf16)
// -> one gather instr covers 8 edges x 128B rows = 16 lines; 2 chains -> 32
// lines outstanding per wave at half the instruction count of round 8.

template <int MODE>
__global__ __launch_bounds__(256) void k_agg(const unsigned short* __restrict__ hs,
                                             const int* __restrict__ row_start,
                                             const int* __restrict__ csr_src,
                                             const float* __restrict__ dinv,
                                             const float* __restrict__ bias,
                                             float* __restrict__ feat) {
  int tid = threadIdx.x;
  int lane = tid & 63;
  int wv = tid >> 6;
  int node = blockIdx.x * 4 + wv;
  int eslot = lane >> 3;  // 0..7
  int ch8 = lane & 7;     // 8-channel group (16B) within 64-ch row
  int r0 = row_start[node];
  int r1 = row_start[node + 1];
  float4 a0 = {0.f, 0.f, 0.f, 0.f}, a1 = a0, b0 = a0, b1 = a0;
  int e = r0 + eslot;
  for (; e + 8 < r1; e += 16) {
    int s0 = csr_src[e];
    int s1 = csr_src[e + 8];
    uint4 v0 = *(const uint4*)(hs + (size_t)s0 * 64 + ch8 * 8);
    uint4 v1 = *(const uint4*)(hs + (size_t)s1 * 64 + ch8 * 8);
    a0.x += bflo(v0.x); a0.y += bfhi(v0.x); a0.z += bflo(v0.y); a0.w += bfhi(v0.y);
    a1.x += bflo(v0.z); a1.y += bfhi(v0.z); a1.z += bflo(v0.w); a1.w += bfhi(v0.w);
    b0.x += bflo(v1.x); b0.y += bfhi(v1.x); b0.z += bflo(v1.y); b0.w += bfhi(v1.y);
    b1.x += bflo(v1.z); b1.y += bfhi(v1.z); b1.z += bflo(v1.w); b1.w += bfhi(v1.w);
  }
  if (e < r1) {
    int s = csr_src[e];
    uint4 v = *(const uint4*)(hs + (size_t)s * 64 + ch8 * 8);
    a0.x += bflo(v.x); a0.y += bfhi(v.x); a0.z += bflo(v.y); a0.w += bfhi(v.y);
    a1.x += bflo(v.z); a1.y += bfhi(v.z); a1.z += bflo(v.w); a1.w += bfhi(v.w);
  }
  float4 v0, v1;
  v0.x = a0.x + b0.x; v0.y = a0.y + b0.y; v0.z = a0.z + b0.z; v0.w = a0.w + b0.w;
  v1.x = a1.x + b1.x; v1.y = a1.y + b1.y; v1.z = a1.z + b1.z; v1.w = a1.w + b1.w;
#pragma unroll
  for (int off = 8; off <= 32; off <<= 1) {
    v0.x += __shfl_xor(v0.x, off, 64);
    v0.y += __shfl_xor(v0.y, off, 64);
    v0.z += __shfl_xor(v0.z, off, 64);
    v0.w += __shfl_xor(v0.w, off, 64);
    v1.x += __shfl_xor(v1.x, off, 64);
    v1.y += __shfl_xor(v1.y, off, 64);
    v1.z += __shfl_xor(v1.z, off, 64);
    v1.w += __shfl_xor(v1.w, off, 64);
  }
  if (lane < 8) {
    uint4 sv = *(const uint4*)(hs + (size_t)node * 64 + ch8 * 8);
    float4 bb0 = *(const float4*)(bias + ch8 * 8);
    float4 bb1 = *(const float4*)(bias + ch8 * 8 + 4);
    float dn = dinv[node];
    float4 t0, t1, o0, o1;
    t0.x = dn * (v0.x + bflo(sv.x)) + bb0.x;
    t0.y = dn * (v0.y + bfhi(sv.x)) + bb0.y;
    t0.z = dn * (v0.z + bflo(sv.y)) + bb0.z;
    t0.w = dn * (v0.w + bfhi(sv.y)) + bb0.w;
    t1.x = dn * (v1.x + bflo(sv.z)) + bb1.x;
    t1.y = dn * (v1.y + bfhi(sv.z)) + bb1.y;
    t1.z = dn * (v1.z + bflo(sv.w)) + bb1.z;
    t1.w = dn * (v1.w + bfhi(sv.w)) + bb1.w;
    float4 l0, l1;
    l0.x = (t0.x >= 0.f) ? t0.x : NEG_SLOPE * t0.x;
    l0.y = (t0.y >= 0.f) ? t0.y : NEG_SLOPE * t0.y;
    l0.z = (t0.z >= 0.f) ? t0.z : NEG_SLOPE * t0.z;
    l0.w = (t0.w >= 0.f) ? t0.w : NEG_SLOPE * t0.w;
    l1.x = (t1.x >= 0.f) ? t1.x : NEG_SLOPE * t1.x;
    l1.y = (t1.y >= 0.f) ? t1.y : NEG_SLOPE * t1.y;
    l1.z = (t1.z >= 0.f) ? t1.z : NEG_SLOPE * t1.z;
    l1.w = (t1.w >= 0.f) ? t1.w : NEG_SLOPE * t1.w;
    if (MODE) {
      o0.x = l0.x + t0.x; o0.y = l0.y + t0.y; o0.z = l0.z + t0.z; o0.w = l0.w + t0.w;
      o1.x = l1.x + t1.x; o1.y = l1.y + t1.y; o1.z = l1.z + t1.z; o1.w = l1.w + t1.w;
    } else {
      o0 = l0; o1 = l1;
    }
    *(float4*)(feat + (size_t)node * 64 + ch8 * 8) = o0;
    *(float4*)(feat + (size_t)node * 64 + ch8 * 8 + 4) = o1;
  }
}

// ---------------- output head (64 -> 1) ----------------

__global__ __launch_bounds__(256) void k_out_xform(const float* __restrict__ feat,
                                                   const float* __restrict__ W_out,
                                                   const float* __restrict__ dinv,
                                                   float* __restrict__ hs1) {
  int lane = threadIdx.x & 63;
  int w = threadIdx.x >> 6;
  int node = blockIdx.x * 4 + w;
  float v = feat[(size_t)node * 64 + lane] * W_out[lane];
#pragma unroll
  for (int off = 32; off; off >>= 1) v += __shfl_xor(v, off, 64);
  if (lane == 0) hs1[node] = v * dinv[node];
}

__global__ __launch_bounds__(256) void k_out_agg(const float* __restrict__ hs1,
                                                 const int* __restrict__ row_start,
                                                 const int* __restrict__ csr_src,
                                                 const float* __restrict__ dinv,
                                                 const float* __restrict__ b_out,
                                                 float* __restrict__ g) {
  int lane = threadIdx.x & 63;
  int w = threadIdx.x >> 6;
  int node = blockIdx.x * 4 + w;
  int r0 = row_start[node];
  int r1 = row_start[node + 1];
  float acc = 0.f;
  for (int e = r0 + lane; e < r1; e += 64) acc += hs1[csr_src[e]];
#pragma unroll
  for (int off = 32; off; off >>= 1) acc += __shfl_xor(acc, off, 64);
  if (lane == 0) {
    float t = dinv[node] * (acc + hs1[node]) + b_out[0];
    g[node] = (t >= 0.f) ? t : NEG_SLOPE * t;
  }
}

// ---------------- FC head ----------------

__global__ __launch_bounds__(128) void k_fc1(const float* __restrict__ g,
                                             const float* __restrict__ fc1_W,
                                             float* __restrict__ h128) {
  int j = threadIdx.x;  // 0..127
  int base = blockIdx.x * 32;
  int end = base + 32;
  if (end > N_NODES) end = N_NODES;
  float acc = 0.f;
  int i = base;
  for (; i + 4 <= end; i += 4) {
    acc += g[i + 0] * fc1_W[(size_t)(i + 0) * 128 + j];
    acc += g[i + 1] * fc1_W[(size_t)(i + 1) * 128 + j];
    acc += g[i + 2] * fc1_W[(size_t)(i + 2) * 128 + j];
    acc += g[i + 3] * fc1_W[(size_t)(i + 3) * 128 + j];
  }
  for (; i < end; i++) acc += g[i] * fc1_W[(size_t)i * 128 + j];
  atomicAdd(&h128[j], acc);
}

__global__ __launch_bounds__(256) void k_fc2(const float* __restrict__ h128raw,
                                             const float* __restrict__ fc1_b,
                                             const float* __restrict__ fc2_W,
                                             const float* __restrict__ fc2_b,
                                             float* __restrict__ out) {
  __shared__ float sh[128];
  int tid = threadIdx.x;
  if (tid < 128) {
    float v = h128raw[tid] + fc1_b[tid];
    sh[tid] = (v > 0.f) ? v : 0.f;
  }
  __syncthreads();
  int p = blockIdx.x * 256 + tid;
  if (p < POI_LEN) {
    float acc = fc2_b[p];
#pragma unroll 8
    for (int j = 0; j < 128; j++) acc += sh[j] * fc2_W[(size_t)j * POI_LEN + p];
    out[p] = (acc > 0.f) ? acc : 0.f;
  }
}

// ---------------- launch ----------------

extern "C" void kernel_launch(void* const* d_in, const int* in_sizes, int n_in,
                              void* d_out, int out_size, void* d_ws, size_t ws_size,
                              hipStream_t stream) {
  const float* x       = (const float*)d_in[0];
  const int*   ei      = (const int*)d_in[1];
  const float* poi_emb = (const float*)d_in[2];
  const float* cat_emb = (const float*)d_in[3];
  const float* W_in    = (const float*)d_in[4];
  const float* b_in    = (const float*)d_in[5];
  const float* gcn_Ws  = (const float*)d_in[6];
  const float* gcn_bs  = (const float*)d_in[7];
  const float* W_out   = (const float*)d_in[8];
  const float* b_out   = (const float*)d_in[9];
  const float* fc1_W   = (const float*)d_in[10];
  const float* fc1_b   = (const float*)d_in[11];
  const float* fc2_W   = (const float*)d_in[12];
  const float* fc2_b   = (const float*)d_in[13];
  const int* src = ei;
  const int* dst = ei + N_EDGES;

  char* p = (char*)d_ws;
  auto take = [&](size_t bytes) {
    char* r = p;
    p += (bytes + 255) & ~(size_t)255;
    return r;
  };
  int*   row_start = (int*)take((size_t)(N_NODES + 1) * 4);
  float* dinv      = (float*)take((size_t)N_NODES * 4);
  int*   bcnt      = (int*)take((size_t)B1 * 4);
  int*   bbase     = (int*)take((size_t)(B1 + 1) * 4);
  int*   csr_src   = (int*)take((size_t)N_EDGES * 4);
  float* feat      = (float*)take((size_t)N_NODES * 64 * 4);
  unsigned short* hs = (unsigned short*)take((size_t)N_NODES * 64 * 2);
  float* proj_poi  = (float*)take((size_t)POI_LEN * 64 * 4);
  float* proj_cat  = (float*)take((size_t)CAT_LEN * 64 * 4);
  float* hs1       = (float*)take((size_t)N_NODES * 4);
  float* g         = (float*)take((size_t)N_NODES * 4);
  float* h128      = (float*)take(128 * 4);
  unsigned short* wf_poi = (unsigned short*)take((size_t)320 * 64 * 2);
  unsigned short* wf_cat = (unsigned short*)take((size_t)128 * 64 * 2);
  unsigned short* wf_gcn = (unsigned short*)take((size_t)5 * 64 * 64 * 2);
  // staging (19.7 MB) aliases feat+hs+proj (24.6 MB) — dead before k_projm runs
  int2* staging = (int2*)feat;
  float* out = (float*)d_out;

  const int nb4 = N_NODES / 4;           // 9583
  const int nb16 = (N_NODES + 15) / 16;  // 2396

  // CSR build first (staging aliases feat/hs/proj regions)
  k_zero<<<2, 256, 0, stream>>>(bcnt, h128);
  k_split<<<NSPLIT, 256, 0, stream>>>(src, dst, bcnt, staging);
  k_bscan<<<1, 256, 0, stream>>>(bcnt, bbase);
  k_place<<<B1, 256, 0, stream>>>(staging, bcnt, bbase, csr_src, row_start, dinv);

  // W pre-swizzle (bf16, B-frag order)
  k_wswz<<<(320 * 64 + 255) / 256, 256, 0, stream>>>(W_in, POI_DIM, 320 * 64, wf_poi);
  k_wswz<<<(128 * 64 + 255) / 256, 256, 0, stream>>>(W_in + 300 * 64, CAT_DIM,
                                                     128 * 64, wf_cat);
  for (int l = 0; l < 5; l++)
    k_wswz<<<(64 * 64 + 255) / 256, 256, 0, stream>>>(
        gcn_Ws + (size_t)l * 64 * 64, 64, 64 * 64, wf_gcn + (size_t)l * 64 * 64);

  // front-end
  k_projm<0, POI_DIM, 320><<<(POI_LEN + 15) / 16, 256, 0, stream>>>(
      poi_emb, wf_poi, proj_poi, POI_LEN, nullptr);
  k_projm<0, CAT_DIM, 128><<<(CAT_LEN + 15) / 16, 256, 0, stream>>>(
      cat_emb, wf_cat, proj_cat, CAT_LEN, nullptr);
  k_gather<<<nb4, 256, 0, stream>>>(x, proj_poi, proj_cat, W_in, dinv, hs);

  k_agg<0><<<nb4, 256, 0, stream>>>(hs, row_start, csr_src, dinv, b_in, feat);
  for (int l = 0; l < 5; l++) {
    k_projm<1, 64, 64><<<nb16, 256, 0, stream>>>(
        feat, wf_gcn + (size_t)l * 64 * 64, hs, N_NODES, dinv);
    k_agg<1><<<nb4, 256, 0, stream>>>(hs, row_start, csr_src, dinv,
                                      gcn_bs + (size_t)l * 64, feat);
  }

  k_out_xform<<<nb4, 256, 0, stream>>>(feat, W_out, dinv, hs1);
  k_out_agg<<<nb4, 256, 0, stream>>>(hs1, row_start, csr_src, dinv, b_out, g);
  k_fc1<<<(N_NODES + 31) / 32, 128, 0, stream>>>(g, fc1_W, h128);
  k_fc2<<<(POI_LEN + 255) / 256, 256, 0, stream>>>(h128, fc1_b, fc2_W, fc2_b, out);
}